// Round 5
// baseline (2915.940 us; speedup 1.0000x reference)
//
#include <hip/hip_runtime.h>
#include <hip/hip_bf16.h>

// ---------------------------------------------------------------------------
// CharRNN: emb -> 4x conv1d(SAME) -> concat -> GRU(256) last state.
//
// Algebraic restructure (conv+Wx+emb linear in one-hot token):
//   xw[b,t,:] = beff + sum_{d=0..4} EmbW[d][X[b,t+d-2]][:]   (f32 tables)
//
// R5: R2/R3/R4 all NaN'd with three different exchange structures; the only
// shared code was the input dtype cast. Reference dtype is float32 -> reading
// buffers as bf16 u16 yields garbage/NaN bf16 words. Fix: runtime dtype
// probe (u16-exponent census on emb_table) + dtype-agnostic weight accessors
// + mode-switched output store. Correct under both f32 and bf16 storage.
// GRU structure = R4 (no cross-block comm): 32 blocks x 4 waves, block owns
// 4 batch rows x all 768 cols; h in LDS split-bf16 hi/lo, parity dbuf;
// Wh persistent in 384 unified VGPR/AGPRs.
// ---------------------------------------------------------------------------

typedef float f32x4 __attribute__((ext_vector_type(4)));
typedef short s16x8 __attribute__((ext_vector_type(8)));
typedef unsigned short u16;
typedef unsigned int   u32;

// ws byte offsets
#define OFF_WC    0u         // f32  [5][64][768]
#define OFF_EMBW  983040u    // f32  [5][128][768]
#define OFF_BEFF  2949120u   // f32  [768]
#define OFF_WHP   2952192u   // bf16 [768][256] (Wh^T)
#define OFF_MODE  3345408u   // int  (0 = bf16 storage, 1 = f32 storage)
#define WS_NEED   3345472u

__device__ __forceinline__ float bf2f(u16 v){
  unsigned u = ((unsigned)v) << 16; return __builtin_bit_cast(float, u);
}
__device__ __forceinline__ u16 f2bf(float f){
  unsigned u = __builtin_bit_cast(unsigned, f);
  unsigned r = u + 0x7FFFu + ((u >> 16) & 1u);
  return (u16)(r >> 16);
}
// dtype-agnostic weight load: element i of a buffer that is either f32 or bf16
__device__ __forceinline__ float ldv(const void* p, int i, int m){
  return m ? ((const float*)p)[i] : bf2f(((const u16*)p)[i]);
}

// ---- probe: detect storage dtype of emb_table ----
__global__ void k_probe(const void* __restrict__ emb, char* ws){
  const u16* w = (const u16*)emb;
  const int ln = threadIdx.x;                 // 64 lanes x 8 words = 512 words
  bool bad = false;
  for (int j = 0; j < 8; ++j){
    u16 v = w[ln*8 + j];
    if (((v >> 7) & 0xFF) >= 0x86) bad = true;  // |bf16| >= 2^7: impossible for emb
  }
  unsigned long long m = __ballot(bad);
  if (ln == 0) *(int*)(ws + OFF_MODE) = (__popcll(m) > 4) ? 1 : 0;
}

// ---- Wc[d][e][j] = sum_br sum_c w_br[d-2+pad][e][c] * Wx[off_br+c][j] ----
__global__ void k_wc(const void* __restrict__ w2, const void* __restrict__ w3,
                     const void* __restrict__ w4, const void* __restrict__ w5,
                     const void* __restrict__ Wx, char* ws){
  const int md = *(const int*)(ws + OFF_MODE);
  const int d = blockIdx.x >> 6;      // 0..4
  const int e = blockIdx.x & 63;      // 0..63
  const int j0 = threadIdx.x;         // 0..255
  const void* wv[4] = {w2,w3,w4,w5};
  const int Kk[4] = {2,3,4,5}, pd[4] = {0,1,1,2};
  float a0=0.f, a1=0.f, a2=0.f;
  for (int br=0; br<4; ++br){
    int k = d - 2 + pd[br];
    if (k < 0 || k >= Kk[br]) continue;
    const int wbase  = (k*64 + e)*128;
    const int wxbase = (br*128)*768;
    for (int c=0; c<128; ++c){
      float wcv = ldv(wv[br], wbase + c, md);
      a0 += wcv * ldv(Wx, wxbase + c*768 + j0      , md);
      a1 += wcv * ldv(Wx, wxbase + c*768 + j0 + 256, md);
      a2 += wcv * ldv(Wx, wxbase + c*768 + j0 + 512, md);
    }
  }
  float* o = (float*)(ws + OFF_WC) + (d*64 + e)*768;
  o[j0] = a0; o[j0+256] = a1; o[j0+512] = a2;
}

// ---- beff[j] = b_in[j] + sum_br sum_c b_br[c]*Wx[off+c][j] ----
__global__ void k_beff(const void* __restrict__ b2, const void* __restrict__ b3,
                       const void* __restrict__ b4, const void* __restrict__ b5,
                       const void* __restrict__ Wx, const void* __restrict__ bin,
                       char* ws){
  const int md = *(const int*)(ws + OFF_MODE);
  int j = blockIdx.x*256 + threadIdx.x;
  if (j >= 768) return;
  const void* bv[4] = {b2,b3,b4,b5};
  float acc = ldv(bin, j, md);
  for (int br=0; br<4; ++br)
    for (int c=0; c<128; ++c)
      acc += ldv(bv[br], c, md) * ldv(Wx, (br*128 + c)*768 + j, md);
  ((float*)(ws + OFF_BEFF))[j] = acc;
}

// ---- EmbW[d][ch][j] = sum_e emb[ch][e] * Wc[d][e][j]  (f32 out) ----
__global__ void k_embw(const void* __restrict__ emb, char* ws){
  const int md = *(const int*)(ws + OFF_MODE);
  const int d = blockIdx.x >> 7, ch = blockIdx.x & 127;
  const float* wc = (const float*)(ws + OFF_WC) + d*64*768;
  float* ew = (float*)(ws + OFF_EMBW) + (size_t)(d*128 + ch)*768;
  const int j0 = threadIdx.x;
  float a0=0.f, a1=0.f, a2=0.f;
  for (int e=0; e<64; ++e){
    float ev = ldv(emb, ch*64 + e, md);
    a0 += ev*wc[e*768 + j0      ];
    a1 += ev*wc[e*768 + j0 + 256];
    a2 += ev*wc[e*768 + j0 + 512];
  }
  ew[j0] = a0; ew[j0+256] = a1; ew[j0+512] = a2;
}

// ---- whp[j][k] = Wh[k][j]  (bf16 out) ----
__global__ void k_whp(const void* __restrict__ Wh, char* ws){
  const int md = *(const int*)(ws + OFF_MODE);
  const int j = blockIdx.x, k = threadIdx.x;
  ((u16*)(ws + OFF_WHP))[j*256 + k] = f2bf(ldv(Wh, k*768 + j, md));
}

// ---- GRU: 32 blocks (4 batch rows each) x 256 threads (4 waves) ----
__launch_bounds__(256, 1)
__global__ void k_gru(const int* __restrict__ X, const void* __restrict__ brec,
                      const char* __restrict__ ws, void* __restrict__ outv){
  const int tid = threadIdx.x;
  const int wv  = tid >> 6, ln = tid & 63;
  const int l15 = ln & 15, l4 = ln >> 4;
  const int g = blockIdx.x;

  const int md = *(const int*)(ws + OFF_MODE);
  const float* embw = (const float*)(ws + OFF_EMBW);
  const float* beff = (const float*)(ws + OFF_BEFF);
  const u16*   whp  = (const u16*)(ws + OFF_WHP);

  __shared__ u16   hbuf[16*272];    // [par(2)][hi/lo(2)][row(4)][272], XOR-swz
  __shared__ float xwlds[4*772];    // [row(4)][768+swz]
  __shared__ float hwlds[4*772];

  // persistent Wh B-frags: (gg=gate, cs=col-slice), col = gg*256+cs*64+wv*16+l15
  s16x8 Bf[3][4][8];
  #pragma unroll
  for (int gg=0; gg<3; ++gg)
    #pragma unroll
    for (int cs=0; cs<4; ++cs){
      const int col = gg*256 + cs*64 + wv*16 + l15;
      #pragma unroll
      for (int q=0; q<8; ++q)
        Bf[gg][cs][q] = *(const s16x8*)(whp + col*256 + q*32 + l4*8);
    }

  const int hc = l4*64 + wv*16 + l15;          // lane-owned h column
  const float br0 = ldv(brec,       hc, md);
  const float br1 = ldv(brec, 256 + hc, md);
  const float br2 = ldv(brec, 512 + hc, md);

  f32x4 be4[3];
  #pragma unroll
  for (int j=0; j<3; ++j) be4[j] = *(const f32x4*)(beff + j*256 + ln*4);

  const int bbase = (g*4 + wv)*512;            // this wave's token row

  for (int i = tid; i < 2176; i += 256) ((u32*)hbuf)[i] = 0u;

  // prologue: xw(t=0) -> xwlds (valid taps d=2..4)
  #pragma unroll
  for (int j=0; j<3; ++j){
    f32x4 v = be4[j];
    #pragma unroll
    for (int d=2; d<5; ++d){
      int ch = X[bbase + (d-2)] & 127;
      v += *(const f32x4*)(embw + (size_t)(d*128 + ch)*768 + j*256 + ln*4);
    }
    const int col = j*256 + ln*4;
    *(f32x4*)&xwlds[wv*772 + (col ^ (((col>>6)&1)<<4))] = v;
  }
  float hprev[4] = {0.f, 0.f, 0.f, 0.f};
  __syncthreads();

  for (int s = 0; s < 512; ++s){
    const int par = s & 1;

    // A) xw(s+1) gather (independent of h; loads hide under MFMA phase)
    f32x4 nxt[3];
    if (s < 511){
      nxt[0] = be4[0]; nxt[1] = be4[1]; nxt[2] = be4[2];
      #pragma unroll
      for (int d=0; d<5; ++d){
        const int tt = s + d - 1;                 // (s+1)+d-2
        if (tt >= 0 && tt < 512){
          const int ch = X[bbase + tt] & 127;
          const float* tp = embw + (size_t)(d*128 + ch)*768 + ln*4;
          nxt[0] += *(const f32x4*)(tp      );
          nxt[1] += *(const f32x4*)(tp + 256);
          nxt[2] += *(const f32x4*)(tp + 512);
        }
      }
    }

    // D) hw = (h_hi + h_lo) @ Wh : 192 MFMAs, A replicated (row m -> h[m&3])
    f32x4 acc[3][4];
    #pragma unroll
    for (int gg=0; gg<3; ++gg)
      #pragma unroll
      for (int cs=0; cs<4; ++cs) acc[gg][cs] = (f32x4){0.f,0.f,0.f,0.f};

    #pragma unroll
    for (int q=0; q<8; ++q){
      const int kb   = q*32 + l4*8;
      const int kswz = ((q>>1)&1)<<5;            // bit6(kb)<<5
      const s16x8 ahi = *(const s16x8*)&hbuf[(par*8 +     (l15&3))*272 + (kb ^ kswz)];
      const s16x8 alo = *(const s16x8*)&hbuf[(par*8 + 4 + (l15&3))*272 + (kb ^ kswz)];
      #pragma unroll
      for (int gg=0; gg<3; ++gg)
        #pragma unroll
        for (int cs=0; cs<4; ++cs)
          acc[gg][cs] = __builtin_amdgcn_mfma_f32_16x16x32_bf16(ahi, Bf[gg][cs][q], acc[gg][cs], 0,0,0);
      #pragma unroll
      for (int gg=0; gg<3; ++gg)
        #pragma unroll
        for (int cs=0; cs<4; ++cs)
          acc[gg][cs] = __builtin_amdgcn_mfma_f32_16x16x32_bf16(alo, Bf[gg][cs][q], acc[gg][cs], 0,0,0);
    }

    // Dw) one lane-quad publishes hw (rows 0..3 live in l4==0 lanes' regs)
    if (l4 == 0){
      #pragma unroll
      for (int gg=0; gg<3; ++gg)
        #pragma unroll
        for (int cs=0; cs<4; ++cs){
          const int c  = gg*256 + cs*64 + wv*16 + l15;
          const int sw = ((c>>6)&1)<<4;
          #pragma unroll
          for (int p=0; p<4; ++p)
            hwlds[p*772 + (c ^ sw)] = acc[gg][cs][p];
        }
    }
    __syncthreads();                              // bar0: hw ready

    // E) gates, lane-parallel: this lane owns h-col hc, batch rows 0..3
    float hn[4];
    {
      const int sw = (l4&1)<<4;                   // bit6(hc)<<4
      #pragma unroll
      for (int p=0; p<4; ++p){
        const float hz = hwlds[p*772 + ((      hc) ^ sw)] + br0;
        const float hr = hwlds[p*772 + ((256 + hc) ^ sw)] + br1;
        const float hh = hwlds[p*772 + ((512 + hc) ^ sw)] + br2;
        const float xz = xwlds[p*772 + ((      hc) ^ sw)];
        const float xr = xwlds[p*772 + ((256 + hc) ^ sw)];
        const float xh = xwlds[p*772 + ((512 + hc) ^ sw)];
        const float z  = 1.f/(1.f + __expf(-(xz + hz)));
        const float r  = 1.f/(1.f + __expf(-(xr + hr)));
        const float pre = xh + r*hh;
        const float e2  = __expf(-2.f*fabsf(pre));
        const float th  = __builtin_copysignf((1.f - e2)/(1.f + e2), pre);
        hn[p] = z*hprev[p] + (1.f - z)*th;
        hprev[p] = hn[p];
      }
    }

    // F) publish h (split-bf16 hi/lo) to parity par^1, or final output
    if (s == 511){
      #pragma unroll
      for (int p=0; p<4; ++p){
        const int idx = (g*4 + p)*256 + hc;
        if (md) ((float*)outv)[idx] = hn[p];
        else    ((u16*)outv)[idx]   = f2bf(hn[p]);
      }
    } else {
      const int ksw = (l4&1)<<5;                  // bit6(hc)<<5
      const int pb  = (par^1)*8;
      #pragma unroll
      for (int p=0; p<4; ++p){
        const u16 bh = f2bf(hn[p]);
        const u16 bl = f2bf(hn[p] - bf2f(bh));
        hbuf[(pb     + p)*272 + (hc ^ ksw)] = bh;
        hbuf[(pb + 4 + p)*272 + (hc ^ ksw)] = bl;
      }
    }
    __syncthreads();                              // bar1: h published, xwlds free

    // W) xw(s+1) -> xwlds
    if (s < 511){
      #pragma unroll
      for (int j=0; j<3; ++j){
        const int col = j*256 + ln*4;
        *(f32x4*)&xwlds[wv*772 + (col ^ (((col>>6)&1)<<4))] = nxt[j];
      }
    }
    __syncthreads();                              // bar2: xw(s+1) ready
  }
}

extern "C" void kernel_launch(void* const* d_in, const int* in_sizes, int n_in,
                              void* d_out, int out_size, void* d_ws, size_t ws_size,
                              hipStream_t stream){
  const int* X = (const int*)d_in[0];
  char* ws = (char*)d_ws;
  if (ws_size < WS_NEED) return;

  k_probe<<<  1,  64, 0, stream>>>(d_in[1], ws);
  k_wc   <<<320, 256, 0, stream>>>(d_in[2], d_in[4], d_in[6], d_in[8], d_in[10], ws);
  k_beff <<<  3, 256, 0, stream>>>(d_in[3], d_in[5], d_in[7], d_in[9], d_in[10], d_in[12], ws);
  k_embw <<<640, 256, 0, stream>>>(d_in[1], ws);
  k_whp  <<<768, 256, 0, stream>>>(d_in[11], ws);
  k_gru  <<< 32, 256, 0, stream>>>(X, d_in[13], ws, d_out);
}

// Round 6
// 2366.390 us; speedup vs baseline: 1.2322x; 1.2322x over previous
//
#include <hip/hip_runtime.h>
#include <hip/hip_bf16.h>

// ---------------------------------------------------------------------------
// CharRNN: emb -> 4x conv1d(SAME) -> concat -> GRU(256) last state.
//
// Algebraic restructure (conv+Wx+emb linear in one-hot token):
//   xw[b,t,:] = beff + sum_{d=0..4} EmbW[d][X[b,t+d-2]][:]   (f32 tables)
//
// R6: R5 passed (absmax 9.8e-4) but k_gru = 2768us: VGPR_Count=256 (at cap;
// Bf needed 384 regs -> spill pressure) and 1 wave/SIMD (no latency hiding).
// Restructure k_gru: 512 threads / 8 waves, __launch_bounds__(512,2):
//  - each wave owns 6 col-tiles -> Bf = 192 regs, fits, no spills
//  - 2 waves/SIMD hide LDS/L2/barrier latency
//  - gates: 2 units/thread over 512 threads
//  - tap gather: 1-2 f32x4 chunks/thread, rolling 5-token X window
//  - 2 barriers/step (xw double-buffered in LDS)
// Numerics identical to R5 (split-bf16 h hi/lo, f32 tables, bf16 Wh).
// ---------------------------------------------------------------------------

typedef float f32x4 __attribute__((ext_vector_type(4)));
typedef short s16x8 __attribute__((ext_vector_type(8)));
typedef unsigned short u16;
typedef unsigned int   u32;

// ws byte offsets
#define OFF_WC    0u         // f32  [5][64][768]
#define OFF_EMBW  983040u    // f32  [5][128][768]
#define OFF_BEFF  2949120u   // f32  [768]
#define OFF_WHP   2952192u   // bf16 [768][256] (Wh^T)
#define OFF_MODE  3345408u   // int  (0 = bf16 storage, 1 = f32 storage)
#define WS_NEED   3345472u

__device__ __forceinline__ float bf2f(u16 v){
  unsigned u = ((unsigned)v) << 16; return __builtin_bit_cast(float, u);
}
__device__ __forceinline__ u16 f2bf(float f){
  unsigned u = __builtin_bit_cast(unsigned, f);
  unsigned r = u + 0x7FFFu + ((u >> 16) & 1u);
  return (u16)(r >> 16);
}
__device__ __forceinline__ float ldv(const void* p, int i, int m){
  return m ? ((const float*)p)[i] : bf2f(((const u16*)p)[i]);
}

// ---- probe: detect storage dtype of emb_table ----
__global__ void k_probe(const void* __restrict__ emb, char* ws){
  const u16* w = (const u16*)emb;
  const int ln = threadIdx.x;
  bool bad = false;
  for (int j = 0; j < 8; ++j){
    u16 v = w[ln*8 + j];
    if (((v >> 7) & 0xFF) >= 0x86) bad = true;  // |bf16| >= 2^7: impossible for emb
  }
  unsigned long long m = __ballot(bad);
  if (ln == 0) *(int*)(ws + OFF_MODE) = (__popcll(m) > 4) ? 1 : 0;
}

// ---- Wc[d][e][j] = sum_br sum_c w_br[d-2+pad][e][c] * Wx[off_br+c][j] ----
__global__ void k_wc(const void* __restrict__ w2, const void* __restrict__ w3,
                     const void* __restrict__ w4, const void* __restrict__ w5,
                     const void* __restrict__ Wx, char* ws){
  const int md = *(const int*)(ws + OFF_MODE);
  const int d = blockIdx.x >> 6;
  const int e = blockIdx.x & 63;
  const int j0 = threadIdx.x;
  const void* wv[4] = {w2,w3,w4,w5};
  const int Kk[4] = {2,3,4,5}, pd[4] = {0,1,1,2};
  float a0=0.f, a1=0.f, a2=0.f;
  for (int br=0; br<4; ++br){
    int k = d - 2 + pd[br];
    if (k < 0 || k >= Kk[br]) continue;
    const int wbase  = (k*64 + e)*128;
    const int wxbase = (br*128)*768;
    for (int c=0; c<128; ++c){
      float wcv = ldv(wv[br], wbase + c, md);
      a0 += wcv * ldv(Wx, wxbase + c*768 + j0      , md);
      a1 += wcv * ldv(Wx, wxbase + c*768 + j0 + 256, md);
      a2 += wcv * ldv(Wx, wxbase + c*768 + j0 + 512, md);
    }
  }
  float* o = (float*)(ws + OFF_WC) + (d*64 + e)*768;
  o[j0] = a0; o[j0+256] = a1; o[j0+512] = a2;
}

// ---- beff[j] = b_in[j] + sum_br sum_c b_br[c]*Wx[off+c][j] ----
__global__ void k_beff(const void* __restrict__ b2, const void* __restrict__ b3,
                       const void* __restrict__ b4, const void* __restrict__ b5,
                       const void* __restrict__ Wx, const void* __restrict__ bin,
                       char* ws){
  const int md = *(const int*)(ws + OFF_MODE);
  int j = blockIdx.x*256 + threadIdx.x;
  if (j >= 768) return;
  const void* bv[4] = {b2,b3,b4,b5};
  float acc = ldv(bin, j, md);
  for (int br=0; br<4; ++br)
    for (int c=0; c<128; ++c)
      acc += ldv(bv[br], c, md) * ldv(Wx, (br*128 + c)*768 + j, md);
  ((float*)(ws + OFF_BEFF))[j] = acc;
}

// ---- EmbW[d][ch][j] = sum_e emb[ch][e] * Wc[d][e][j]  (f32 out) ----
__global__ void k_embw(const void* __restrict__ emb, char* ws){
  const int md = *(const int*)(ws + OFF_MODE);
  const int d = blockIdx.x >> 7, ch = blockIdx.x & 127;
  const float* wc = (const float*)(ws + OFF_WC) + d*64*768;
  float* ew = (float*)(ws + OFF_EMBW) + (size_t)(d*128 + ch)*768;
  const int j0 = threadIdx.x;
  float a0=0.f, a1=0.f, a2=0.f;
  for (int e=0; e<64; ++e){
    float ev = ldv(emb, ch*64 + e, md);
    a0 += ev*wc[e*768 + j0      ];
    a1 += ev*wc[e*768 + j0 + 256];
    a2 += ev*wc[e*768 + j0 + 512];
  }
  ew[j0] = a0; ew[j0+256] = a1; ew[j0+512] = a2;
}

// ---- whp[j][k] = Wh[k][j]  (bf16 out) ----
__global__ void k_whp(const void* __restrict__ Wh, char* ws){
  const int md = *(const int*)(ws + OFF_MODE);
  const int j = blockIdx.x, k = threadIdx.x;
  ((u16*)(ws + OFF_WHP))[j*256 + k] = f2bf(ldv(Wh, k*768 + j, md));
}

// ---- GRU: 32 blocks (4 batch rows each) x 512 threads (8 waves) ----
__launch_bounds__(512, 2)
__global__ void k_gru(const int* __restrict__ X, const void* __restrict__ brec,
                      const char* __restrict__ ws, void* __restrict__ outv){
  const int tid = threadIdx.x;
  const int wv  = tid >> 6, ln = tid & 63;
  const int l15 = ln & 15, l4 = ln >> 4;
  const int g = blockIdx.x;

  const int md = *(const int*)(ws + OFF_MODE);
  const float* embw = (const float*)(ws + OFF_EMBW);
  const float* beff = (const float*)(ws + OFF_BEFF);
  const u16*   whp  = (const u16*)(ws + OFF_WHP);

  __shared__ u16   hbuf[16*272];       // [par(2)][hi/lo(2)][brow(4)][272] swz
  __shared__ float xwlds[2][4][772];   // [buf][brow][768+swz]
  __shared__ float hwlds[4][772];

  // persistent Wh B-frags: wave owns tiles t = wv*6 + i, cols t*16 + l15
  s16x8 Bf[6][8];
  #pragma unroll
  for (int i=0; i<6; ++i){
    const int col = (wv*6 + i)*16 + l15;
    #pragma unroll
    for (int q=0; q<8; ++q)
      Bf[i][q] = *(const s16x8*)(whp + col*256 + q*32 + l4*8);
  }

  // ---- gate-side assignment: units (row1,hcol) and (row1+2,hcol) ----
  const int hcol = tid & 255;
  const int row1 = tid >> 8;           // 0..1; second unit row = row1+2
  const float br0 = ldv(brec,       hcol, md);
  const float br1 = ldv(brec, 256 + hcol, md);
  const float br2 = ldv(brec, 512 + hcol, md);
  const int gsw  = ((hcol>>6)&1)<<4;   // xw/hw lds swizzle for this col
  const int ksw  = ((hcol>>6)&1)<<5;   // hbuf k-swizzle for this col

  // ---- gather-side assignment ----
  const int grow  = wv >> 1;                            // gather row 0..3
  const int heavy = (((wv & 1) ^ ((wv >> 2) & 1)) == 0);// SIMD-balanced
  const int c1 = heavy ? ln : 64 + ln;                  // chunk in [0,192)
  const int c2 = 128 + ln;                              // heavy only
  const f32x4 be1 = *(const f32x4*)(beff + c1*4);
  const f32x4 be2 = *(const f32x4*)(beff + c2*4);
  const int bbase = (g*4 + grow)*512;

  // rolling token window: before step s, w0..w4 = X[s-1 .. s+3]
  int w0 = 0;
  int w1 = X[bbase + 0] & 127;
  int w2 = X[bbase + 1] & 127;
  int w3 = X[bbase + 2] & 127;
  int w4 = X[bbase + 3] & 127;

  for (int i = tid; i < 2176; i += 512) ((u32*)hbuf)[i] = 0u;

  // prologue: xw(0) -> xwlds[0]  (taps d=2..4 -> t=0..2)
  {
    f32x4 v1 = be1, v2 = be2;
    #pragma unroll
    for (int d=2; d<5; ++d){
      const int ch = X[bbase + (d-2)] & 127;
      const float* tp = embw + (size_t)(d*128 + ch)*768;
      v1 += *(const f32x4*)(tp + c1*4);
      if (heavy) v2 += *(const f32x4*)(tp + c2*4);
    }
    const int o1 = c1*4, o2 = c2*4;
    *(f32x4*)&xwlds[0][grow][o1 ^ (((o1>>6)&1)<<4)] = v1;
    if (heavy) *(f32x4*)&xwlds[0][grow][o2 ^ (((o2>>6)&1)<<4)] = v2;
  }
  float hpA = 0.f, hpB = 0.f;          // hprev for units (row1, row1+2)
  __syncthreads();

  for (int s = 0; s < 512; ++s){
    const int par = s & 1;

    // D) hw = (h_hi + h_lo) @ Wh : 96 MFMAs/wave over 6 owned col-tiles
    f32x4 acc[6];
    #pragma unroll
    for (int i=0; i<6; ++i) acc[i] = (f32x4){0.f,0.f,0.f,0.f};
    #pragma unroll
    for (int q=0; q<8; ++q){
      const int kb = q*32 + l4*8;
      const int kz = ((q>>1)&1)<<5;
      const s16x8 ahi = *(const s16x8*)&hbuf[(par*8 +     (l15&3))*272 + (kb ^ kz)];
      const s16x8 alo = *(const s16x8*)&hbuf[(par*8 + 4 + (l15&3))*272 + (kb ^ kz)];
      #pragma unroll
      for (int i=0; i<6; ++i)
        acc[i] = __builtin_amdgcn_mfma_f32_16x16x32_bf16(ahi, Bf[i][q], acc[i], 0,0,0);
      #pragma unroll
      for (int i=0; i<6; ++i)
        acc[i] = __builtin_amdgcn_mfma_f32_16x16x32_bf16(alo, Bf[i][q], acc[i], 0,0,0);
    }
    // publish hw (rows 0..3 valid in l4==0 lanes)
    if (l4 == 0){
      #pragma unroll
      for (int i=0; i<6; ++i){
        const int col = (wv*6 + i)*16 + l15;
        const int sw  = ((col>>6)&1)<<4;
        #pragma unroll
        for (int p=0; p<4; ++p)
          hwlds[p][col ^ sw] = acc[i][p];
      }
    }
    __syncthreads();                              // bar0: hwlds ready

    // A) gather xw(s+1): issue loads first (latency overlaps gates below)
    f32x4 n1, n2;
    if (s < 511){
      n1 = be1; n2 = be2;
      const int tk[5] = {w0, w1, w2, w3, w4};
      #pragma unroll
      for (int d=0; d<5; ++d){
        if ((unsigned)(s - 1 + d) < 512u){
          const float* tp = embw + (size_t)(d*128 + tk[d])*768;
          n1 += *(const f32x4*)(tp + c1*4);
          if (heavy) n2 += *(const f32x4*)(tp + c2*4);
        }
      }
      // shift window, load X[s+4]
      w0 = w1; w1 = w2; w2 = w3; w3 = w4;
      if (s + 4 < 512) w4 = X[bbase + s + 4] & 127;
    }

    // E) gates: 2 units/thread: (row1, hcol), (row1+2, hcol)
    float hnA, hnB;
    #pragma unroll
    for (int u=0; u<2; ++u){
      const int row = row1 + u*2;
      const float hz = hwlds[row][(      hcol) ^ gsw] + br0;
      const float hr = hwlds[row][(256 + hcol) ^ gsw] + br1;
      const float hh = hwlds[row][(512 + hcol) ^ gsw] + br2;
      const float xz = xwlds[par][row][(      hcol) ^ gsw];
      const float xr = xwlds[par][row][(256 + hcol) ^ gsw];
      const float xh = xwlds[par][row][(512 + hcol) ^ gsw];
      const float hp = u ? hpB : hpA;
      const float z  = 1.f/(1.f + __expf(-(xz + hz)));
      const float r  = 1.f/(1.f + __expf(-(xr + hr)));
      const float pre = xh + r*hh;
      const float e2  = __expf(-2.f*fabsf(pre));
      const float th  = __builtin_copysignf((1.f - e2)/(1.f + e2), pre);
      const float hn  = z*hp + (1.f - z)*th;
      if (u) hnB = hn; else hnA = hn;
    }
    hpA = hnA; hpB = hnB;

    // F) publish h (split-bf16) to parity par^1, or final output
    if (s == 511){
      const int idx = (g*4 + row1)*256 + hcol;
      if (md){ ((float*)outv)[idx] = hnA; ((float*)outv)[idx + 512] = hnB; }
      else   { ((u16*)outv)[idx] = f2bf(hnA); ((u16*)outv)[idx + 512] = f2bf(hnB); }
    } else {
      const int pb = (par^1)*8;
      #pragma unroll
      for (int u=0; u<2; ++u){
        const int row = row1 + u*2;
        const float hn = u ? hnB : hnA;
        const u16 bh = f2bf(hn);
        const u16 bl = f2bf(hn - bf2f(bh));
        hbuf[(pb     + row)*272 + (hcol ^ ksw)] = bh;
        hbuf[(pb + 4 + row)*272 + (hcol ^ ksw)] = bl;
      }
      // W) xw(s+1) -> other buffer
      const int o1 = c1*4, o2 = c2*4;
      *(f32x4*)&xwlds[par^1][grow][o1 ^ (((o1>>6)&1)<<4)] = n1;
      if (heavy) *(f32x4*)&xwlds[par^1][grow][o2 ^ (((o2>>6)&1)<<4)] = n2;
    }
    __syncthreads();                              // bar1: h(s+1), xw(s+1) ready
  }
}

extern "C" void kernel_launch(void* const* d_in, const int* in_sizes, int n_in,
                              void* d_out, int out_size, void* d_ws, size_t ws_size,
                              hipStream_t stream){
  const int* X = (const int*)d_in[0];
  char* ws = (char*)d_ws;
  if (ws_size < WS_NEED) return;

  k_probe<<<  1,  64, 0, stream>>>(d_in[1], ws);
  k_wc   <<<320, 256, 0, stream>>>(d_in[2], d_in[4], d_in[6], d_in[8], d_in[10], ws);
  k_beff <<<  3, 256, 0, stream>>>(d_in[3], d_in[5], d_in[7], d_in[9], d_in[10], d_in[12], ws);
  k_embw <<<640, 256, 0, stream>>>(d_in[1], ws);
  k_whp  <<<768, 256, 0, stream>>>(d_in[11], ws);
  k_gru  <<< 32, 512, 0, stream>>>(X, d_in[13], ws, d_out);
}

// Round 7
// 2324.956 us; speedup vs baseline: 1.2542x; 1.0178x over previous
//
#include <hip/hip_runtime.h>
#include <hip/hip_bf16.h>

// ---------------------------------------------------------------------------
// CharRNN: emb -> 4x conv1d(SAME) -> concat -> GRU(256) last state.
//
// Algebraic restructure (conv+Wx+emb linear in one-hot token):
//   xw[b,t,:] = beff + sum_{d=0..4} EmbW[d][X[b,t+d-2]][:]   (f32 tables)
//
// R7: R6's VGPR_Count=128 exposed hipcc __launch_bounds__ 2nd-arg semantics =
// min BLOCKS/CU (CUDA-style): (512,2) -> 4 waves/SIMD -> 128-reg cap -> all
// 48 Bf fragments spilled to scratch, reloaded every step (~10k cyc/step).
// Fix: (512,1) -> 2 waves/SIMD -> 256-reg cap; trim demand to ~245:
//  - no rolling token window (X loads are L1-broadcast)
//  - beff reloaded per step (L1-hot) instead of persistent regs
//  - tap gather issued at top of step, hides under MFMA phase
// Numerics identical to R5/R6 (split-bf16 h hi/lo, f32 tables, bf16 Wh).
// ---------------------------------------------------------------------------

typedef float f32x4 __attribute__((ext_vector_type(4)));
typedef short s16x8 __attribute__((ext_vector_type(8)));
typedef unsigned short u16;
typedef unsigned int   u32;

// ws byte offsets
#define OFF_WC    0u         // f32  [5][64][768]
#define OFF_EMBW  983040u    // f32  [5][128][768]
#define OFF_BEFF  2949120u   // f32  [768]
#define OFF_WHP   2952192u   // bf16 [768][256] (Wh^T)
#define OFF_MODE  3345408u   // int  (0 = bf16 storage, 1 = f32 storage)
#define WS_NEED   3345472u

__device__ __forceinline__ float bf2f(u16 v){
  unsigned u = ((unsigned)v) << 16; return __builtin_bit_cast(float, u);
}
__device__ __forceinline__ u16 f2bf(float f){
  unsigned u = __builtin_bit_cast(unsigned, f);
  unsigned r = u + 0x7FFFu + ((u >> 16) & 1u);
  return (u16)(r >> 16);
}
__device__ __forceinline__ float ldv(const void* p, int i, int m){
  return m ? ((const float*)p)[i] : bf2f(((const u16*)p)[i]);
}

// ---- probe: detect storage dtype of emb_table ----
__global__ void k_probe(const void* __restrict__ emb, char* ws){
  const u16* w = (const u16*)emb;
  const int ln = threadIdx.x;
  bool bad = false;
  for (int j = 0; j < 8; ++j){
    u16 v = w[ln*8 + j];
    if (((v >> 7) & 0xFF) >= 0x86) bad = true;  // |bf16| >= 2^7: impossible for emb
  }
  unsigned long long m = __ballot(bad);
  if (ln == 0) *(int*)(ws + OFF_MODE) = (__popcll(m) > 4) ? 1 : 0;
}

// ---- Wc[d][e][j] = sum_br sum_c w_br[d-2+pad][e][c] * Wx[off_br+c][j] ----
__global__ void k_wc(const void* __restrict__ w2, const void* __restrict__ w3,
                     const void* __restrict__ w4, const void* __restrict__ w5,
                     const void* __restrict__ Wx, char* ws){
  const int md = *(const int*)(ws + OFF_MODE);
  const int d = blockIdx.x >> 6;
  const int e = blockIdx.x & 63;
  const int j0 = threadIdx.x;
  const void* wv[4] = {w2,w3,w4,w5};
  const int Kk[4] = {2,3,4,5}, pd[4] = {0,1,1,2};
  float a0=0.f, a1=0.f, a2=0.f;
  for (int br=0; br<4; ++br){
    int k = d - 2 + pd[br];
    if (k < 0 || k >= Kk[br]) continue;
    const int wbase  = (k*64 + e)*128;
    const int wxbase = (br*128)*768;
    for (int c=0; c<128; ++c){
      float wcv = ldv(wv[br], wbase + c, md);
      a0 += wcv * ldv(Wx, wxbase + c*768 + j0      , md);
      a1 += wcv * ldv(Wx, wxbase + c*768 + j0 + 256, md);
      a2 += wcv * ldv(Wx, wxbase + c*768 + j0 + 512, md);
    }
  }
  float* o = (float*)(ws + OFF_WC) + (d*64 + e)*768;
  o[j0] = a0; o[j0+256] = a1; o[j0+512] = a2;
}

// ---- beff[j] = b_in[j] + sum_br sum_c b_br[c]*Wx[off+c][j] ----
__global__ void k_beff(const void* __restrict__ b2, const void* __restrict__ b3,
                       const void* __restrict__ b4, const void* __restrict__ b5,
                       const void* __restrict__ Wx, const void* __restrict__ bin,
                       char* ws){
  const int md = *(const int*)(ws + OFF_MODE);
  int j = blockIdx.x*256 + threadIdx.x;
  if (j >= 768) return;
  const void* bv[4] = {b2,b3,b4,b5};
  float acc = ldv(bin, j, md);
  for (int br=0; br<4; ++br)
    for (int c=0; c<128; ++c)
      acc += ldv(bv[br], c, md) * ldv(Wx, (br*128 + c)*768 + j, md);
  ((float*)(ws + OFF_BEFF))[j] = acc;
}

// ---- EmbW[d][ch][j] = sum_e emb[ch][e] * Wc[d][e][j]  (f32 out) ----
__global__ void k_embw(const void* __restrict__ emb, char* ws){
  const int md = *(const int*)(ws + OFF_MODE);
  const int d = blockIdx.x >> 7, ch = blockIdx.x & 127;
  const float* wc = (const float*)(ws + OFF_WC) + d*64*768;
  float* ew = (float*)(ws + OFF_EMBW) + (size_t)(d*128 + ch)*768;
  const int j0 = threadIdx.x;
  float a0=0.f, a1=0.f, a2=0.f;
  for (int e=0; e<64; ++e){
    float ev = ldv(emb, ch*64 + e, md);
    a0 += ev*wc[e*768 + j0      ];
    a1 += ev*wc[e*768 + j0 + 256];
    a2 += ev*wc[e*768 + j0 + 512];
  }
  ew[j0] = a0; ew[j0+256] = a1; ew[j0+512] = a2;
}

// ---- whp[j][k] = Wh[k][j]  (bf16 out) ----
__global__ void k_whp(const void* __restrict__ Wh, char* ws){
  const int md = *(const int*)(ws + OFF_MODE);
  const int j = blockIdx.x, k = threadIdx.x;
  ((u16*)(ws + OFF_WHP))[j*256 + k] = f2bf(ldv(Wh, k*768 + j, md));
}

// ---- GRU: 32 blocks (4 batch rows each) x 512 threads (8 waves) ----
__launch_bounds__(512, 1)
__global__ void k_gru(const int* __restrict__ X, const void* __restrict__ brec,
                      const char* __restrict__ ws, void* __restrict__ outv){
  const int tid = threadIdx.x;
  const int wv  = tid >> 6, ln = tid & 63;
  const int l15 = ln & 15, l4 = ln >> 4;
  const int g = blockIdx.x;

  const int md = *(const int*)(ws + OFF_MODE);
  const float* embw = (const float*)(ws + OFF_EMBW);
  const float* beff = (const float*)(ws + OFF_BEFF);
  const u16*   whp  = (const u16*)(ws + OFF_WHP);

  __shared__ u16   hbuf[16*272];       // [par(2)][hi/lo(2)][brow(4)][272] swz
  __shared__ float xwlds[2][4][772];   // [buf][brow][768+swz]
  __shared__ float hwlds[4][772];

  // persistent Wh B-frags: wave owns tiles t = wv*6 + i, cols t*16 + l15
  s16x8 Bf[6][8];
  #pragma unroll
  for (int i=0; i<6; ++i){
    const int col = (wv*6 + i)*16 + l15;
    #pragma unroll
    for (int q=0; q<8; ++q)
      Bf[i][q] = *(const s16x8*)(whp + col*256 + q*32 + l4*8);
  }

  // ---- gate-side assignment: units (row1,hcol) and (row1+2,hcol) ----
  const int hcol = tid & 255;
  const int row1 = tid >> 8;           // 0..1; second unit row = row1+2
  const float br0 = ldv(brec,       hcol, md);
  const float br1 = ldv(brec, 256 + hcol, md);
  const float br2 = ldv(brec, 512 + hcol, md);
  const int gsw  = ((hcol>>6)&1)<<4;   // xw/hw lds swizzle for this col
  const int ksw  = ((hcol>>6)&1)<<5;   // hbuf k-swizzle for this col

  // ---- gather-side assignment ----
  const int grow  = wv >> 1;                            // gather row 0..3
  const int heavy = (((wv & 1) ^ ((wv >> 2) & 1)) == 0);// SIMD-balanced
  const int c1 = heavy ? ln : 64 + ln;                  // chunk in [0,192)
  const int c2 = 128 + ln;                              // heavy only
  const int bbase = (g*4 + grow)*512;

  for (int i = tid; i < 2176; i += 512) ((u32*)hbuf)[i] = 0u;

  // prologue: xw(0) -> xwlds[0]  (taps d=2..4 -> t=0..2)
  {
    f32x4 v1 = *(const f32x4*)(beff + c1*4);
    f32x4 v2 = heavy ? *(const f32x4*)(beff + c2*4) : (f32x4){0.f,0.f,0.f,0.f};
    #pragma unroll
    for (int d=2; d<5; ++d){
      const int ch = X[bbase + (d-2)] & 127;
      const float* tp = embw + (size_t)(d*128 + ch)*768;
      v1 += *(const f32x4*)(tp + c1*4);
      if (heavy) v2 += *(const f32x4*)(tp + c2*4);
    }
    const int o1 = c1*4, o2 = c2*4;
    *(f32x4*)&xwlds[0][grow][o1 ^ (((o1>>6)&1)<<4)] = v1;
    if (heavy) *(f32x4*)&xwlds[0][grow][o2 ^ (((o2>>6)&1)<<4)] = v2;
  }
  float hpA = 0.f, hpB = 0.f;          // hprev for units (row1, row1+2)
  __syncthreads();

  for (int s = 0; s < 512; ++s){
    const int par = s & 1;

    // A) gather xw(s+1): issue loads FIRST (L2 latency hides under MFMAs)
    f32x4 n1, n2;
    if (s < 511){
      n1 = *(const f32x4*)(beff + c1*4);
      n2 = heavy ? *(const f32x4*)(beff + c2*4) : (f32x4){0.f,0.f,0.f,0.f};
      #pragma unroll
      for (int d=0; d<5; ++d){
        const int t = s - 1 + d;                  // (s+1)+d-2
        if ((unsigned)t < 512u){
          const int ch = X[bbase + t] & 127;
          const float* tp = embw + (size_t)(d*128 + ch)*768;
          n1 += *(const f32x4*)(tp + c1*4);
          if (heavy) n2 += *(const f32x4*)(tp + c2*4);
        }
      }
    }

    // D) hw = (h_hi + h_lo) @ Wh : 96 MFMAs/wave over 6 owned col-tiles
    f32x4 acc[6];
    #pragma unroll
    for (int i=0; i<6; ++i) acc[i] = (f32x4){0.f,0.f,0.f,0.f};
    #pragma unroll
    for (int q=0; q<8; ++q){
      const int kb = q*32 + l4*8;
      const int kz = ((q>>1)&1)<<5;
      const s16x8 ahi = *(const s16x8*)&hbuf[(par*8 +     (l15&3))*272 + (kb ^ kz)];
      const s16x8 alo = *(const s16x8*)&hbuf[(par*8 + 4 + (l15&3))*272 + (kb ^ kz)];
      #pragma unroll
      for (int i=0; i<6; ++i)
        acc[i] = __builtin_amdgcn_mfma_f32_16x16x32_bf16(ahi, Bf[i][q], acc[i], 0,0,0);
      #pragma unroll
      for (int i=0; i<6; ++i)
        acc[i] = __builtin_amdgcn_mfma_f32_16x16x32_bf16(alo, Bf[i][q], acc[i], 0,0,0);
    }
    // publish hw (rows 0..3 valid in l4==0 lanes)
    if (l4 == 0){
      #pragma unroll
      for (int i=0; i<6; ++i){
        const int col = (wv*6 + i)*16 + l15;
        const int sw  = ((col>>6)&1)<<4;
        #pragma unroll
        for (int p=0; p<4; ++p)
          hwlds[p][col ^ sw] = acc[i][p];
      }
    }
    __syncthreads();                              // bar0: hwlds ready

    // E) gates: 2 units/thread: (row1, hcol), (row1+2, hcol)
    float hnA, hnB;
    #pragma unroll
    for (int u=0; u<2; ++u){
      const int row = row1 + u*2;
      const float hz = hwlds[row][(      hcol) ^ gsw] + br0;
      const float hr = hwlds[row][(256 + hcol) ^ gsw] + br1;
      const float hh = hwlds[row][(512 + hcol) ^ gsw] + br2;
      const float xz = xwlds[par][row][(      hcol) ^ gsw];
      const float xr = xwlds[par][row][(256 + hcol) ^ gsw];
      const float xh = xwlds[par][row][(512 + hcol) ^ gsw];
      const float hp = u ? hpB : hpA;
      const float z  = 1.f/(1.f + __expf(-(xz + hz)));
      const float r  = 1.f/(1.f + __expf(-(xr + hr)));
      const float pre = xh + r*hh;
      const float e2  = __expf(-2.f*fabsf(pre));
      const float th  = __builtin_copysignf((1.f - e2)/(1.f + e2), pre);
      const float hn  = z*hp + (1.f - z)*th;
      if (u) hnB = hn; else hnA = hn;
    }
    hpA = hnA; hpB = hnB;

    // F) publish h (split-bf16) to parity par^1, or final output
    if (s == 511){
      const int idx = (g*4 + row1)*256 + hcol;
      if (md){ ((float*)outv)[idx] = hnA; ((float*)outv)[idx + 512] = hnB; }
      else   { ((u16*)outv)[idx] = f2bf(hnA); ((u16*)outv)[idx + 512] = f2bf(hnB); }
    } else {
      const int pb = (par^1)*8;
      #pragma unroll
      for (int u=0; u<2; ++u){
        const int row = row1 + u*2;
        const float hn = u ? hnB : hnA;
        const u16 bh = f2bf(hn);
        const u16 bl = f2bf(hn - bf2f(bh));
        hbuf[(pb     + row)*272 + (hcol ^ ksw)] = bh;
        hbuf[(pb + 4 + row)*272 + (hcol ^ ksw)] = bl;
      }
      // W) xw(s+1) -> other buffer
      const int o1 = c1*4, o2 = c2*4;
      *(f32x4*)&xwlds[par^1][grow][o1 ^ (((o1>>6)&1)<<4)] = n1;
      if (heavy) *(f32x4*)&xwlds[par^1][grow][o2 ^ (((o2>>6)&1)<<4)] = n2;
    }
    __syncthreads();                              // bar1: h(s+1), xw(s+1) ready
  }
}

extern "C" void kernel_launch(void* const* d_in, const int* in_sizes, int n_in,
                              void* d_out, int out_size, void* d_ws, size_t ws_size,
                              hipStream_t stream){
  const int* X = (const int*)d_in[0];
  char* ws = (char*)d_ws;
  if (ws_size < WS_NEED) return;

  k_probe<<<  1,  64, 0, stream>>>(d_in[1], ws);
  k_wc   <<<320, 256, 0, stream>>>(d_in[2], d_in[4], d_in[6], d_in[8], d_in[10], ws);
  k_beff <<<  3, 256, 0, stream>>>(d_in[3], d_in[5], d_in[7], d_in[9], d_in[10], d_in[12], ws);
  k_embw <<<640, 256, 0, stream>>>(d_in[1], ws);
  k_whp  <<<768, 256, 0, stream>>>(d_in[11], ws);
  k_gru  <<< 32, 512, 0, stream>>>(X, d_in[13], ws, d_out);
}